// Round 1
// baseline (835.170 us; speedup 1.0000x reference)
//
#include <hip/hip_runtime.h>
#include <hip/hip_bf16.h>

// PINN forward + exact u_x, u_xx via analytic dual-of-dual propagation.
// N=262144 samples, MLP 1->50(x4 hidden 50->50, tanh)->100, then
// out = u - dt * (f @ alpha^T), f = -l1*u*u_x + exp(l2)*u_xx.

#define NPTS 262144
#define HW   50
#define Q    100
#define CH   10
#define BLK  64
#define NBLK (NPTS / BLK)

__device__ __forceinline__ float fast_tanh(float z) {
    // tanh(z) = 1 - 2/(exp(2z)+1); saturates correctly for |z| large.
    float e = __expf(2.0f * z);
    return 1.0f - __fdividef(2.0f, e + 1.0f);
}

__global__ void __launch_bounds__(BLK, 2)
pinn_fused(const float* __restrict__ W0, const float* __restrict__ b0,
           const float* __restrict__ W1, const float* __restrict__ b1,
           const float* __restrict__ W2, const float* __restrict__ b2,
           const float* __restrict__ W3, const float* __restrict__ b3,
           const float* __restrict__ W4, const float* __restrict__ b4,
           const float* __restrict__ W5, const float* __restrict__ b5,
           const float* __restrict__ x,
           const float* __restrict__ lam1p, const float* __restrict__ lam2p,
           const float* __restrict__ alpha, const float* __restrict__ dtp,
           float* __restrict__ out)
{
    // 12.8 KB: layer staging as fp32 [50][64]; later aliased as bf16 f-staging
    // [100][64] (exactly the same byte count). Each thread touches ONLY its own
    // column -> no barriers, no bank conflicts (lane-consecutive addresses).
    __shared__ float stage[HW * BLK];
    __hip_bfloat16* fstage = (__hip_bfloat16*)stage;

    const int tid = threadIdx.x;
    const int n = blockIdx.x * BLK + tid;

    float h[HW], hx[HW], hxx[HW];
    const float xv = x[n];

    // ---- layer 0: 1 -> 50, tanh. h=x, h_x=1, h_xx=0 entering.
#pragma unroll
    for (int j = 0; j < HW; ++j) {
        float w = W0[j];
        float t = fast_tanh(fmaf(xv, w, b0[j]));
        float s = 1.0f - t * t;
        h[j]   = t;
        hx[j]  = s * w;
        hxx[j] = -2.0f * t * s * w * w;
    }

    // ---- 4 hidden layers 50 -> 50, tanh, with derivative streams.
    for (int L = 0; L < 4; ++L) {
        const float* W; const float* b;
        if      (L == 0) { W = W1; b = b1; }
        else if (L == 1) { W = W2; b = b2; }
        else if (L == 2) { W = W3; b = b3; }
        else             { W = W4; b = b4; }

        // value pass: t = tanh(h@W + b) -> stage
        for (int jc = 0; jc < HW / CH; ++jc) {
            float acc[CH];
#pragma unroll
            for (int k = 0; k < CH; ++k) acc[k] = b[jc * CH + k];
#pragma unroll
            for (int i = 0; i < HW; ++i) {
                float hi = h[i];
#pragma unroll
                for (int k = 0; k < CH; ++k)
                    acc[k] = fmaf(hi, W[i * HW + jc * CH + k], acc[k]);
            }
#pragma unroll
            for (int k = 0; k < CH; ++k)
                stage[(jc * CH + k) * BLK + tid] = fast_tanh(acc[k]);
        }
#pragma unroll
        for (int j = 0; j < HW; ++j) h[j] = stage[j * BLK + tid];  // h := t

        // dx pass: zx = hx@W -> stage (raw)
        for (int jc = 0; jc < HW / CH; ++jc) {
            float acc[CH];
#pragma unroll
            for (int k = 0; k < CH; ++k) acc[k] = 0.0f;
#pragma unroll
            for (int i = 0; i < HW; ++i) {
                float hi = hx[i];
#pragma unroll
                for (int k = 0; k < CH; ++k)
                    acc[k] = fmaf(hi, W[i * HW + jc * CH + k], acc[k]);
            }
#pragma unroll
            for (int k = 0; k < CH; ++k)
                stage[(jc * CH + k) * BLK + tid] = acc[k];
        }
#pragma unroll
        for (int j = 0; j < HW; ++j) hx[j] = stage[j * BLK + tid];  // hx := zx

        // dxx pass: zxx = hxx@W -> stage (raw)
        for (int jc = 0; jc < HW / CH; ++jc) {
            float acc[CH];
#pragma unroll
            for (int k = 0; k < CH; ++k) acc[k] = 0.0f;
#pragma unroll
            for (int i = 0; i < HW; ++i) {
                float hi = hxx[i];
#pragma unroll
                for (int k = 0; k < CH; ++k)
                    acc[k] = fmaf(hi, W[i * HW + jc * CH + k], acc[k]);
            }
#pragma unroll
            for (int k = 0; k < CH; ++k)
                stage[(jc * CH + k) * BLK + tid] = acc[k];
        }
#pragma unroll
        for (int j = 0; j < HW; ++j) hxx[j] = stage[j * BLK + tid]; // hxx := zxx

        // combine through tanh: s=1-t^2; hx=s*zx; hxx=s*zxx - 2*t*s*zx^2
#pragma unroll
        for (int j = 0; j < HW; ++j) {
            float t = h[j];
            float s = 1.0f - t * t;
            float zx = hx[j];
            float zxx = hxx[j];
            hx[j]  = s * zx;
            hxx[j] = fmaf(s, zxx, -2.0f * t * s * zx * zx);
        }
    }

    // ---- final linear 50 -> 100 (3 streams), f, stage f (bf16), u -> out (temp)
    const float lam1 = lam1p[0];
    const float el2  = __expf(lam2p[0]);
    const float dt   = dtp[0];

    for (int qc = 0; qc < Q / CH; ++qc) {
        float u[CH], ux[CH], uxx[CH];
#pragma unroll
        for (int k = 0; k < CH; ++k) { u[k] = b5[qc * CH + k]; ux[k] = 0.0f; uxx[k] = 0.0f; }
#pragma unroll
        for (int i = 0; i < HW; ++i) {
            float a = h[i], bx = hx[i], cxx = hxx[i];
#pragma unroll
            for (int k = 0; k < CH; ++k) {
                float w = W5[i * Q + qc * CH + k];
                u[k]   = fmaf(a,   w, u[k]);
                ux[k]  = fmaf(bx,  w, ux[k]);
                uxx[k] = fmaf(cxx, w, uxx[k]);
            }
        }
#pragma unroll
        for (int k = 0; k < CH; ++k) {
            float f = fmaf(-lam1 * u[k], ux[k], el2 * uxx[k]);
            fstage[(qc * CH + k) * BLK + tid] = __float2bfloat16(f);
            out[(size_t)n * Q + qc * CH + k] = u[k];   // temp store of u (exact fp32)
        }
    }

    // ---- out[n,q] = u[n,q] - dt * sum_j f[n,j] * alpha[q,j]
    for (int qc = 0; qc < Q / CH; ++qc) {
        float acc[CH];
#pragma unroll
        for (int k = 0; k < CH; ++k) acc[k] = 0.0f;
        for (int j = 0; j < Q; ++j) {
            float fj = __bfloat162float(fstage[j * BLK + tid]);
#pragma unroll
            for (int k = 0; k < CH; ++k)
                acc[k] = fmaf(fj, alpha[(qc * CH + k) * Q + j], acc[k]);
        }
#pragma unroll
        for (int k = 0; k < CH; ++k) {
            size_t o = (size_t)n * Q + qc * CH + k;
            out[o] = fmaf(-dt, acc[k], out[o]);
        }
    }
}

extern "C" void kernel_launch(void* const* d_in, const int* in_sizes, int n_in,
                              void* d_out, int out_size, void* d_ws, size_t ws_size,
                              hipStream_t stream) {
    const float* W0 = (const float*)d_in[0];
    const float* b0 = (const float*)d_in[1];
    const float* W1 = (const float*)d_in[2];
    const float* b1 = (const float*)d_in[3];
    const float* W2 = (const float*)d_in[4];
    const float* b2 = (const float*)d_in[5];
    const float* W3 = (const float*)d_in[6];
    const float* b3 = (const float*)d_in[7];
    const float* W4 = (const float*)d_in[8];
    const float* b4 = (const float*)d_in[9];
    const float* W5 = (const float*)d_in[10];
    const float* b5 = (const float*)d_in[11];
    const float* x    = (const float*)d_in[12];
    const float* lam1 = (const float*)d_in[13];
    const float* lam2 = (const float*)d_in[14];
    const float* alpha = (const float*)d_in[15];
    const float* dt   = (const float*)d_in[16];

    pinn_fused<<<NBLK, BLK, 0, stream>>>(W0, b0, W1, b1, W2, b2, W3, b3, W4, b4,
                                         W5, b5, x, lam1, lam2, alpha, dt,
                                         (float*)d_out);
}

// Round 2
// 170.506 us; speedup vs baseline: 4.8982x; 4.8982x over previous
//
#include <hip/hip_runtime.h>
#include <hip/hip_bf16.h>

// PINN via MFMA: per-wave 32 samples. State (h,hx,hxx) as bf16 B-fragments in
// registers; weights as block-shared LDS A-fragments (Wt orientation, hi/lo
// split for the value stream); C[ch][samp] orientation so frags are shared
// across the 3 derivative streams. out = u - dt*(f @ alpha^T).

#define NPTS 262144
#define HW   50
#define Q    100
#define BLK  256
#define WAVES 4
#define SPW  32
#define SPB  128
#define NBLK (NPTS / SPB)

typedef float f32x4 __attribute__((ext_vector_type(4)));
typedef short bf16x8 __attribute__((ext_vector_type(8)));

__device__ __forceinline__ unsigned int f2bf(float f) {
    unsigned int u = __builtin_bit_cast(unsigned int, f);
    return (u + 0x7FFFu + ((u >> 16) & 1u)) >> 16;   // RNE, finite inputs
}
__device__ __forceinline__ float bf2f(unsigned int b) {
    unsigned int u = b << 16;
    return __builtin_bit_cast(float, u);
}
__device__ __forceinline__ float fast_tanh(float z) {
    float e = __expf(2.0f * z);
    return 1.0f - __fdividef(2.0f, e + 1.0f);
}

// Build A-fragments into LDS, frag-ready for ds_read_b128.
// A[m][k] = trans ? src[k*ld + m] : src[m*ld + k], zero-padded.
// slot(fid=kt*nmt+mt) at wfrag + fid*1024 + lane*16 (hi); +nf*1024 for lo.
__device__ __forceinline__ void prep_frags(unsigned char* wfrag, const float* src,
                                           int nmt, int nkt, int kmax, int mmax,
                                           int ld, bool want_lo, bool trans, int tid)
{
    const int nf = nmt * nkt;
    for (int p = tid; p < nf * 64; p += BLK) {
        int ln  = p & 63;
        int fid = p >> 6;
        int kt  = fid / nmt;
        int mt  = fid - kt * nmt;
        int gg  = ln >> 4;
        int m   = mt * 16 + (ln & 15);
        int kb  = kt * 32 + gg * 8;
        unsigned int hw[4], lw[4];
#pragma unroll
        for (int jj = 0; jj < 4; ++jj) {
            int k0 = kb + 2 * jj, k1 = k0 + 1;
            float v0 = 0.0f, v1 = 0.0f;
            if (k0 < kmax && m < mmax) v0 = trans ? src[k0 * ld + m] : src[m * ld + k0];
            if (k1 < kmax && m < mmax) v1 = trans ? src[k1 * ld + m] : src[m * ld + k1];
            unsigned int h0 = f2bf(v0), h1 = f2bf(v1);
            hw[jj] = h0 | (h1 << 16);
            if (want_lo) {
                unsigned int l0 = f2bf(v0 - bf2f(h0));
                unsigned int l1 = f2bf(v1 - bf2f(h1));
                lw[jj] = l0 | (l1 << 16);
            }
        }
        *(uint4*)(wfrag + fid * 1024 + ln * 16) = make_uint4(hw[0], hw[1], hw[2], hw[3]);
        if (want_lo)
            *(uint4*)(wfrag + (nf + fid) * 1024 + ln * 16) = make_uint4(lw[0], lw[1], lw[2], lw[3]);
    }
}

__global__ void __launch_bounds__(BLK, 2)
pinn_mfma(const float* __restrict__ W0, const float* __restrict__ b0,
          const float* __restrict__ W1, const float* __restrict__ b1,
          const float* __restrict__ W2, const float* __restrict__ b2,
          const float* __restrict__ W3, const float* __restrict__ b3,
          const float* __restrict__ W4, const float* __restrict__ b4,
          const float* __restrict__ W5, const float* __restrict__ b5,
          const float* __restrict__ x, const float* __restrict__ lam1p,
          const float* __restrict__ lam2p, const float* __restrict__ alpha,
          const float* __restrict__ dtp, float* __restrict__ out)
{
    __shared__ __align__(16) unsigned char wfrag[28 * 1024];
    __shared__ __align__(16) unsigned char statebuf[WAVES][8192];

    const int tid  = threadIdx.x;
    const int w    = tid >> 6;
    const int lane = tid & 63;
    const int l15  = lane & 15;
    const int g    = lane >> 4;
    const int sbase = blockIdx.x * SPB + w * SPW;

    unsigned char* st0 = &statebuf[w][0];
    unsigned char* st1 = &statebuf[w][4096];
    const int swz = (l15 & 7) << 4;   // samp&7 == l15&7 (samp = 16nt + l15)

    const f32x4 Z4 = {0.0f, 0.0f, 0.0f, 0.0f};

    // persistent state B-fragments: B[k=ch][n=samp], elem j -> ch = 32kt+8g+j
    bf16x8 Bh_hi[2][2], Bh_lo[2][2], Bx[2][2], Bxx[2][2];

    // ---------- layer 0: 1 -> 50 (analytic, elementwise) ----------
    {
        float xv[2];
#pragma unroll
        for (int nt = 0; nt < 2; ++nt) xv[nt] = x[sbase + nt * 16 + l15];
#pragma unroll
        for (int kt = 0; kt < 2; ++kt) {
            float wv[8], bv[8];
#pragma unroll
            for (int j = 0; j < 8; ++j) {
                int ch = kt * 32 + g * 8 + j;
                wv[j] = (ch < HW) ? W0[ch] : 0.0f;
                bv[j] = (ch < HW) ? b0[ch] : 0.0f;
            }
#pragma unroll
            for (int nt = 0; nt < 2; ++nt) {
#pragma unroll
                for (int j = 0; j < 8; ++j) {
                    float t = fast_tanh(fmaf(xv[nt], wv[j], bv[j]));
                    float s = 1.0f - t * t;
                    float hx = s * wv[j];
                    float hxx = -2.0f * t * hx * wv[j];
                    unsigned int hi = f2bf(t);
                    unsigned int lo = f2bf(t - bf2f(hi));
                    Bh_hi[kt][nt][j] = (short)hi;
                    Bh_lo[kt][nt][j] = (short)lo;
                    Bx[kt][nt][j]   = (short)f2bf(hx);
                    Bxx[kt][nt][j]  = (short)f2bf(hxx);
                }
            }
        }
    }

    // ---------- 4 hidden layers 50 -> 50 ----------
    for (int L = 0; L < 4; ++L) {
        const float *Wl, *bl;
        if      (L == 0) { Wl = W1; bl = b1; }
        else if (L == 1) { Wl = W2; bl = b2; }
        else if (L == 2) { Wl = W3; bl = b3; }
        else             { Wl = W4; bl = b4; }

        __syncthreads();
        prep_frags(wfrag, Wl, 4, 2, HW, HW, HW, true, true, tid);
        __syncthreads();

        float bb[4][4];
#pragma unroll
        for (int mt = 0; mt < 4; ++mt)
#pragma unroll
            for (int r = 0; r < 4; ++r) {
                int ch = mt * 16 + g * 4 + r;
                bb[mt][r] = (ch < HW) ? bl[ch] : 0.0f;
            }

        f32x4 at[4][2], ax[4][2], axx[4][2];
#pragma unroll
        for (int mt = 0; mt < 4; ++mt)
#pragma unroll
            for (int nt = 0; nt < 2; ++nt) { at[mt][nt] = Z4; ax[mt][nt] = Z4; axx[mt][nt] = Z4; }

#pragma unroll
        for (int kt = 0; kt < 2; ++kt) {
#pragma unroll
            for (int mt = 0; mt < 4; ++mt) {
                bf16x8 Ahi = *(const bf16x8*)(wfrag + (kt * 4 + mt) * 1024 + lane * 16);
                bf16x8 Alo = *(const bf16x8*)(wfrag + (8 + kt * 4 + mt) * 1024 + lane * 16);
#pragma unroll
                for (int nt = 0; nt < 2; ++nt) {
                    at[mt][nt]  = __builtin_amdgcn_mfma_f32_16x16x32_bf16(Ahi, Bh_hi[kt][nt], at[mt][nt], 0, 0, 0);
                    at[mt][nt]  = __builtin_amdgcn_mfma_f32_16x16x32_bf16(Ahi, Bh_lo[kt][nt], at[mt][nt], 0, 0, 0);
                    at[mt][nt]  = __builtin_amdgcn_mfma_f32_16x16x32_bf16(Alo, Bh_hi[kt][nt], at[mt][nt], 0, 0, 0);
                    ax[mt][nt]  = __builtin_amdgcn_mfma_f32_16x16x32_bf16(Ahi, Bx[kt][nt],  ax[mt][nt],  0, 0, 0);
                    axx[mt][nt] = __builtin_amdgcn_mfma_f32_16x16x32_bf16(Ahi, Bxx[kt][nt], axx[mt][nt], 0, 0, 0);
                }
            }
        }

        // phase A: t = tanh(z + b); stage hi/lo -> read new Bh frags
#pragma unroll
        for (int mt = 0; mt < 4; ++mt)
#pragma unroll
            for (int nt = 0; nt < 2; ++nt) {
                unsigned int h0 = 0, h1 = 0, l0 = 0, l1 = 0;
#pragma unroll
                for (int r = 0; r < 4; ++r) {
                    float t = fast_tanh(at[mt][nt][r] + bb[mt][r]);
                    at[mt][nt][r] = t;
                    unsigned int hi = f2bf(t);
                    unsigned int lo = f2bf(t - bf2f(hi));
                    if (r < 2) { h0 |= hi << (16 * r);      l0 |= lo << (16 * r); }
                    else       { h1 |= hi << (16 * (r-2));  l1 |= lo << (16 * (r-2)); }
                }
                int off = ((nt * 16 + l15) * 128 + (mt * 16 + g * 4) * 2) ^ swz;
                *(uint2*)(st0 + off) = make_uint2(h0, h1);
                *(uint2*)(st1 + off) = make_uint2(l0, l1);
            }
#pragma unroll
        for (int kt = 0; kt < 2; ++kt)
#pragma unroll
            for (int nt = 0; nt < 2; ++nt) {
                int off = ((nt * 16 + l15) * 128 + (kt * 32 + g * 8) * 2) ^ swz;
                Bh_hi[kt][nt] = *(const bf16x8*)(st0 + off);
                Bh_lo[kt][nt] = *(const bf16x8*)(st1 + off);
            }
        asm volatile("s_waitcnt lgkmcnt(0)" ::: "memory");

        // phase B: hx = s*zx ; hxx = s*zxx - 2*t*s*zx^2
#pragma unroll
        for (int mt = 0; mt < 4; ++mt)
#pragma unroll
            for (int nt = 0; nt < 2; ++nt) {
                unsigned int a0 = 0, a1 = 0, c0 = 0, c1 = 0;
#pragma unroll
                for (int r = 0; r < 4; ++r) {
                    float t   = at[mt][nt][r];
                    float s   = 1.0f - t * t;
                    float zx  = ax[mt][nt][r];
                    float zxx = axx[mt][nt][r];
                    float hxn  = s * zx;
                    float hxxn = fmaf(s, zxx, -2.0f * t * zx * hxn);
                    unsigned int ux  = f2bf(hxn);
                    unsigned int uxx = f2bf(hxxn);
                    if (r < 2) { a0 |= ux << (16 * r);      c0 |= uxx << (16 * r); }
                    else       { a1 |= ux << (16 * (r-2));  c1 |= uxx << (16 * (r-2)); }
                }
                int off = ((nt * 16 + l15) * 128 + (mt * 16 + g * 4) * 2) ^ swz;
                *(uint2*)(st0 + off) = make_uint2(a0, a1);
                *(uint2*)(st1 + off) = make_uint2(c0, c1);
            }
#pragma unroll
        for (int kt = 0; kt < 2; ++kt)
#pragma unroll
            for (int nt = 0; nt < 2; ++nt) {
                int off = ((nt * 16 + l15) * 128 + (kt * 32 + g * 8) * 2) ^ swz;
                Bx[kt][nt]  = *(const bf16x8*)(st0 + off);
                Bxx[kt][nt] = *(const bf16x8*)(st1 + off);
            }
        asm volatile("s_waitcnt lgkmcnt(0)" ::: "memory");
    }

    // ---------- final layer 50 -> 100 + f, staged bf16 ----------
    __syncthreads();
    prep_frags(wfrag, W5, 7, 2, HW, Q, Q, true, true, tid);
    __syncthreads();

    const float lam1 = lam1p[0];
    const float el2  = __expf(lam2p[0]);
    const float dtv  = dtp[0];

    f32x4 u_all[7][2];
    // f-stage: [32 samp][128 j] bf16, 8KB = st0..st1, swizzled
#pragma unroll
    for (int mt = 0; mt < 7; ++mt) {
        f32x4 au[2], aux_[2], auxx[2];
#pragma unroll
        for (int nt = 0; nt < 2; ++nt) { au[nt] = Z4; aux_[nt] = Z4; auxx[nt] = Z4; }
#pragma unroll
        for (int kt = 0; kt < 2; ++kt) {
            bf16x8 Ahi = *(const bf16x8*)(wfrag + (kt * 7 + mt) * 1024 + lane * 16);
            bf16x8 Alo = *(const bf16x8*)(wfrag + (14 + kt * 7 + mt) * 1024 + lane * 16);
#pragma unroll
            for (int nt = 0; nt < 2; ++nt) {
                au[nt]   = __builtin_amdgcn_mfma_f32_16x16x32_bf16(Ahi, Bh_hi[kt][nt], au[nt],   0, 0, 0);
                au[nt]   = __builtin_amdgcn_mfma_f32_16x16x32_bf16(Ahi, Bh_lo[kt][nt], au[nt],   0, 0, 0);
                au[nt]   = __builtin_amdgcn_mfma_f32_16x16x32_bf16(Alo, Bh_hi[kt][nt], au[nt],   0, 0, 0);
                aux_[nt] = __builtin_amdgcn_mfma_f32_16x16x32_bf16(Ahi, Bx[kt][nt],  aux_[nt], 0, 0, 0);
                auxx[nt] = __builtin_amdgcn_mfma_f32_16x16x32_bf16(Ahi, Bxx[kt][nt], auxx[nt], 0, 0, 0);
            }
        }
        float b5v[4];
#pragma unroll
        for (int r = 0; r < 4; ++r) {
            int q = mt * 16 + g * 4 + r;
            b5v[r] = (q < Q) ? b5[q] : 0.0f;
        }
#pragma unroll
        for (int nt = 0; nt < 2; ++nt) {
            unsigned int f0 = 0, f1 = 0;
#pragma unroll
            for (int r = 0; r < 4; ++r) {
                int q = mt * 16 + g * 4 + r;
                float u   = au[nt][r] + b5v[r];
                float f   = fmaf(-lam1 * u, aux_[nt][r], el2 * auxx[nt][r]);
                if (q >= Q) f = 0.0f;     // zero-pad j>=100 for the alpha GEMM
                u_all[mt][nt][r] = u;
                unsigned int fb = f2bf(f);
                if (r < 2) f0 |= fb << (16 * r); else f1 |= fb << (16 * (r - 2));
            }
            int s = nt * 16 + l15;
            int off = (s * 256 + (mt * 16 + g * 4) * 2) ^ swz;
            *(uint2*)(st0 + off) = make_uint2(f0, f1);
        }
    }

    // ---------- alpha GEMM: corr[q][samp] = sum_j alpha[q][j] f[j][samp] ----------
    __syncthreads();
    prep_frags(wfrag, alpha, 7, 4, Q, Q, Q, false, false, tid);
    __syncthreads();

    bf16x8 Ff[4][2];
#pragma unroll
    for (int kt = 0; kt < 4; ++kt)
#pragma unroll
        for (int nt = 0; nt < 2; ++nt) {
            int s = nt * 16 + l15;
            int off = (s * 256 + (kt * 32 + g * 8) * 2) ^ swz;
            Ff[kt][nt] = *(const bf16x8*)(st0 + off);
        }
    asm volatile("s_waitcnt lgkmcnt(0)" ::: "memory");

    // out-stage reuses st0: [32 samp][16 q] fp32 (2KB)
#pragma unroll
    for (int mt = 0; mt < 7; ++mt) {
        f32x4 ac[2]; ac[0] = Z4; ac[1] = Z4;
#pragma unroll
        for (int kt = 0; kt < 4; ++kt) {
            bf16x8 Aa = *(const bf16x8*)(wfrag + (kt * 7 + mt) * 1024 + lane * 16);
#pragma unroll
            for (int nt = 0; nt < 2; ++nt)
                ac[nt] = __builtin_amdgcn_mfma_f32_16x16x32_bf16(Aa, Ff[kt][nt], ac[nt], 0, 0, 0);
        }
#pragma unroll
        for (int nt = 0; nt < 2; ++nt) {
            int s = nt * 16 + l15;
            f32x4 ov;
#pragma unroll
            for (int r = 0; r < 4; ++r)
                ov[r] = fmaf(-dtv, ac[nt][r], u_all[mt][nt][r]);
            *(f32x4*)(st0 + s * 64 + g * 16) = ov;
        }
        asm volatile("s_waitcnt lgkmcnt(0)" ::: "memory");
#pragma unroll
        for (int p = 0; p < 2; ++p) {
            int s  = p * 16 + (lane >> 2);
            int qi = (lane & 3) * 4;
            f32x4 v = *(const f32x4*)(st0 + s * 64 + qi * 4);
            int qb = mt * 16 + qi;
            if (qb < Q)
                *(f32x4*)(&out[(size_t)(sbase + s) * Q + qb]) = v;   // 16B aligned: 400%16==0
        }
        asm volatile("s_waitcnt lgkmcnt(0)" ::: "memory");   // reads done before next mt overwrites
    }
}

extern "C" void kernel_launch(void* const* d_in, const int* in_sizes, int n_in,
                              void* d_out, int out_size, void* d_ws, size_t ws_size,
                              hipStream_t stream) {
    const float* W0 = (const float*)d_in[0];
    const float* b0 = (const float*)d_in[1];
    const float* W1 = (const float*)d_in[2];
    const float* b1 = (const float*)d_in[3];
    const float* W2 = (const float*)d_in[4];
    const float* b2 = (const float*)d_in[5];
    const float* W3 = (const float*)d_in[6];
    const float* b3 = (const float*)d_in[7];
    const float* W4 = (const float*)d_in[8];
    const float* b4 = (const float*)d_in[9];
    const float* W5 = (const float*)d_in[10];
    const float* b5 = (const float*)d_in[11];
    const float* x     = (const float*)d_in[12];
    const float* lam1  = (const float*)d_in[13];
    const float* lam2  = (const float*)d_in[14];
    const float* alpha = (const float*)d_in[15];
    const float* dt    = (const float*)d_in[16];

    pinn_mfma<<<NBLK, BLK, 0, stream>>>(W0, b0, W1, b1, W2, b2, W3, b3, W4, b4,
                                        W5, b5, x, lam1, lam2, alpha, dt,
                                        (float*)d_out);
}